// Round 2
// baseline (810.522 us; speedup 1.0000x reference)
//
#include <hip/hip_runtime.h>

// PolynomialSketch: out[b,o] = (1/64)*exp(0.5*lv) * prod_k( sum_i x[b,i]*exp(-lls)*W[k,i,o] )
// B=16384, D_IN=1024, D_FEAT=4096, DEGREE=3

#define BATCH 16384
#define DIN   1024
#define DFEAT 4096

typedef short short8 __attribute__((ext_vector_type(8)));
typedef float f32x4  __attribute__((ext_vector_type(4)));
typedef unsigned short ushort8v __attribute__((ext_vector_type(8)));

__device__ __forceinline__ unsigned short f2bf(float f) {
  unsigned int u = __float_as_uint(f);
  u += 0x7FFFu + ((u >> 16) & 1u);   // round-to-nearest-even
  return (unsigned short)(u >> 16);
}

// ---- prelude 1: xs_bf16[b,i] = bf16(x[b,i] * exp(-log_ls)) ----
__global__ void cast_x_kernel(const float4* __restrict__ x,
                              const float* __restrict__ log_ls,
                              ushort8v* __restrict__ xs) {
  float inv = expf(-log_ls[0]);
  int i = blockIdx.x * 256 + threadIdx.x;
  float4 v0 = x[i * 2];
  float4 v1 = x[i * 2 + 1];
  ushort8v o;
  o[0] = f2bf(v0.x * inv); o[1] = f2bf(v0.y * inv);
  o[2] = f2bf(v0.z * inv); o[3] = f2bf(v0.w * inv);
  o[4] = f2bf(v1.x * inv); o[5] = f2bf(v1.y * inv);
  o[6] = f2bf(v1.z * inv); o[7] = f2bf(v1.w * inv);
  xs[i] = o;
}

// ---- prelude 2: Wt[d, o, i] = bf16(W[d, i, o]) ----
__global__ void transpose_w_kernel(const float* __restrict__ W,
                                   unsigned short* __restrict__ Wt) {
  __shared__ float tile[32][65];
  int d  = blockIdx.z;
  int i0 = blockIdx.y * 32;   // d_in
  int o0 = blockIdx.x * 64;   // d_feat
  int tid = threadIdx.x;      // 0..255
  const float* src = W + (size_t)d * DIN * DFEAT + (size_t)i0 * DFEAT + o0;
  #pragma unroll
  for (int j = 0; j < 2; ++j) {
    int idx = j * 256 + tid;       // 0..511
    int r = idx >> 4;              // i row 0..31
    int c = (idx & 15) * 4;        // o col
    float4 v = *(const float4*)(src + (size_t)r * DFEAT + c);
    tile[r][c + 0] = v.x; tile[r][c + 1] = v.y;
    tile[r][c + 2] = v.z; tile[r][c + 3] = v.w;
  }
  __syncthreads();
  unsigned short* dst = Wt + (size_t)d * DFEAT * DIN + (size_t)o0 * DIN + i0;
  #pragma unroll
  for (int j = 0; j < 2; ++j) {
    int idx = j * 256 + tid;
    int r = idx >> 3;              // o row 0..63
    int c = (idx & 7) * 4;         // i col
    ushort4 u;
    u.x = f2bf(tile[c + 0][r]);
    u.y = f2bf(tile[c + 1][r]);
    u.z = f2bf(tile[c + 2][r]);
    u.w = f2bf(tile[c + 3][r]);
    *(ushort4*)(dst + (size_t)r * DIN + c) = u;
  }
}

// ---- main fused kernel ----
// BM=128, BN=128, BK=64. 512 threads = 8 waves in 2x4; wave tile 64x32 per degree.
// Double-buffered LDS (128 KiB), 3 phases per K-tile (one per degree matrix),
// counted vmcnt (never 0 in main loop), setprio around MFMA clusters.
// Stage-group issue order per tile: {A, B0}[4], {B1}[2], {B2}[2] per wave, so:
//   P0 entry: outstanding = 8, need A+B0 of cur tile -> vmcnt(4)
//   P1 entry: outstanding = 8, need B1 (oldest 2)    -> vmcnt(6)
//   P2 entry: outstanding = 8, need B2 (oldest 2)    -> vmcnt(6)
// Phase entry order is STRICT: waitcnt (own loads landed) -> s_barrier (all
// waves' loads landed) -> sched_barrier(0) (compiler fence: ds_reads must not
// be hoisted between waitcnt and barrier — rule #18 class hazard).
// LDS tiles: rows of 8 16B-chunks, chunk-XOR-swizzled: phys p = c ^ (row&7),
// applied on the GLOBAL source address (global_load_lds dest must be linear).
__global__ __launch_bounds__(512, 2) void sketch_gemm_kernel(
    const unsigned short* __restrict__ xs,   // [16384][1024] bf16 bits
    const unsigned short* __restrict__ Wt,   // [3][4096][1024] bf16 bits
    const float* __restrict__ log_var,
    float* __restrict__ out) {               // [16384][4096] fp32
  __shared__ unsigned short As[2][128 * 64];       // 32 KB
  __shared__ unsigned short Bs[2][3][128 * 64];    // 96 KB

  const int tid  = threadIdx.x;
  const int lane = tid & 63;
  const int w    = tid >> 6;      // 0..7
  const int wm   = w >> 2;        // wave row (0..1)
  const int wn   = w & 3;         // wave col (0..3)
  const int row  = lane & 15;
  const int quad = lane >> 4;

  // XCD-aware mapping: bid % 8 -> XCD. Each XCD owns 4 bn blocks
  // (B slice = 4*128*1024*2B*3 = 3 MB, fits 4 MB per-XCD L2). Within an
  // XCD, 4 consecutive blocks share one bm (A tile reused from L2).
  int bid = blockIdx.x;
  int xcd = bid & 7;
  int t0  = bid >> 3;                // 0..511 per XCD
  int bn  = (xcd << 2) + (t0 & 3);   // 0..31
  int bm  = t0 >> 2;                 // 0..127

  f32x4 acc[3][4][2];
  #pragma unroll
  for (int d = 0; d < 3; ++d)
    #pragma unroll
    for (int mi = 0; mi < 4; ++mi)
      #pragma unroll
      for (int ni = 0; ni < 2; ++ni)
        acc[d][mi][ni] = (f32x4){0.f, 0.f, 0.f, 0.f};

  const unsigned short* xsrc = xs + (size_t)(bm * 128) * DIN;
  const unsigned short* wsrc = Wt + (size_t)(bn * 128) * DIN;

#define STAGE_A(DSTBUF, K0)                                                    \
  {                                                                            \
    _Pragma("unroll")                                                          \
    for (int j = 0; j < 2; ++j) {                                              \
      int gi = (w << 1) + j;                                                   \
      int gc = (gi << 6) + lane;                                               \
      int mm = gc >> 3;                                                        \
      int cc = (gc & 7) ^ (mm & 7);                                            \
      __builtin_amdgcn_global_load_lds(                                        \
          (const __attribute__((address_space(1))) void*)(                     \
              xsrc + (size_t)mm * DIN + (K0) + cc * 8),                        \
          (__attribute__((address_space(3))) void*)(&As[DSTBUF][gi << 9]),     \
          16, 0, 0);                                                           \
    }                                                                          \
  }

#define STAGE_B(DSTBUF, MAT, K0)                                               \
  {                                                                            \
    _Pragma("unroll")                                                          \
    for (int j = 0; j < 2; ++j) {                                              \
      int gi = (w << 1) + j;                                                   \
      int gc = (gi << 6) + lane;                                               \
      int nn = gc >> 3;                                                        \
      int cc = (gc & 7) ^ (nn & 7);                                            \
      __builtin_amdgcn_global_load_lds(                                        \
          (const __attribute__((address_space(1))) void*)(                     \
              wsrc + (size_t)(MAT) * (DFEAT * DIN) + (size_t)nn * DIN + (K0) + cc * 8), \
          (__attribute__((address_space(3))) void*)(&Bs[DSTBUF][MAT][gi << 9]),\
          16, 0, 0);                                                           \
    }                                                                          \
  }

#define READ_A(SRCBUF)                                                         \
  _Pragma("unroll")                                                            \
  for (int mi = 0; mi < 4; ++mi) {                                             \
    _Pragma("unroll")                                                          \
    for (int kh = 0; kh < 2; ++kh) {                                           \
      int mm = wm * 64 + mi * 16 + row;                                        \
      int pp = ((kh << 2) + quad) ^ (mm & 7);                                  \
      a[mi][kh] = *(const short8*)(&As[SRCBUF][mm * 64 + pp * 8]);             \
    }                                                                          \
  }

#define READ_B(SRCBUF, MAT)                                                    \
  _Pragma("unroll")                                                            \
  for (int ni = 0; ni < 2; ++ni) {                                             \
    _Pragma("unroll")                                                          \
    for (int kh = 0; kh < 2; ++kh) {                                           \
      int nn = wn * 32 + ni * 16 + row;                                        \
      int pp = ((kh << 2) + quad) ^ (nn & 7);                                  \
      b[ni][kh] = *(const short8*)(&Bs[SRCBUF][MAT][nn * 64 + pp * 8]);        \
    }                                                                          \
  }

#define MFMA_PHASE(MAT)                                                        \
  __builtin_amdgcn_s_setprio(1);                                               \
  _Pragma("unroll")                                                            \
  for (int mi = 0; mi < 4; ++mi)                                               \
    _Pragma("unroll")                                                          \
    for (int ni = 0; ni < 2; ++ni)                                             \
      _Pragma("unroll")                                                        \
      for (int kh = 0; kh < 2; ++kh)                                           \
        acc[MAT][mi][ni] = __builtin_amdgcn_mfma_f32_16x16x32_bf16(            \
            a[mi][kh], b[ni][kh], acc[MAT][mi][ni], 0, 0, 0);                  \
  __builtin_amdgcn_s_setprio(0);

#define PHASE_ENTRY(N)                                                         \
  asm volatile("s_waitcnt vmcnt(" #N ")" ::: "memory");                        \
  __builtin_amdgcn_s_barrier();                                                \
  __builtin_amdgcn_sched_barrier(0);

  short8 a[4][2];
  short8 b[2][2];

  // prologue: stage tile 0 into buf 0 (issue order A, B0, B1, B2)
  STAGE_A(0, 0);
  STAGE_B(0, 0, 0);
  STAGE_B(0, 1, 0);
  STAGE_B(0, 2, 0);

  for (int t = 0; t < 15; ++t) {
    const int cur = t & 1;
    const int nxt = cur ^ 1;
    const int kn  = (t + 1) << 6;

    // ---- P0: mat0; prefetch A(t+1), B0(t+1) ----
    PHASE_ENTRY(4);                     // A(t)+B0(t) landed (own), barrier = all
    STAGE_A(nxt, kn);
    STAGE_B(nxt, 0, kn);
    READ_A(cur);
    READ_B(cur, 0);
    MFMA_PHASE(0);

    // ---- P1: mat1; prefetch B1(t+1) ----
    PHASE_ENTRY(6);                     // B1(t) landed
    STAGE_B(nxt, 1, kn);
    READ_B(cur, 1);
    MFMA_PHASE(1);

    // ---- P2: mat2; prefetch B2(t+1) ----
    PHASE_ENTRY(6);                     // B2(t) landed
    STAGE_B(nxt, 2, kn);
    READ_B(cur, 2);
    MFMA_PHASE(2);
  }

  // ---- peeled last tile (t = 15, buf 1, no prefetch; drain 4/2/0) ----
  PHASE_ENTRY(4);
  READ_A(1);
  READ_B(1, 0);
  MFMA_PHASE(0);

  PHASE_ENTRY(2);
  READ_B(1, 1);
  MFMA_PHASE(1);

  PHASE_ENTRY(0);
  READ_B(1, 2);
  MFMA_PHASE(2);

  // epilogue: out = acc0*acc1*acc2 * (1/64)*exp(0.5*lv)
  float sc = 0.015625f * expf(0.5f * log_var[0]);
  #pragma unroll
  for (int mi = 0; mi < 4; ++mi) {
    #pragma unroll
    for (int ni = 0; ni < 2; ++ni) {
      int colg = bn * 128 + wn * 32 + ni * 16 + row;
      int rowg = bm * 128 + wm * 64 + mi * 16 + quad * 4;
      #pragma unroll
      for (int t2 = 0; t2 < 4; ++t2) {
        float v = acc[0][mi][ni][t2] * acc[1][mi][ni][t2] * acc[2][mi][ni][t2] * sc;
        out[(size_t)(rowg + t2) * DFEAT + colg] = v;
      }
    }
  }
#undef STAGE_A
#undef STAGE_B
#undef READ_A
#undef READ_B
#undef MFMA_PHASE
#undef PHASE_ENTRY
}

extern "C" void kernel_launch(void* const* d_in, const int* in_sizes, int n_in,
                              void* d_out, int out_size, void* d_ws, size_t ws_size,
                              hipStream_t stream) {
  const float* x   = (const float*)d_in[0];
  const float* W   = (const float*)d_in[1];
  const float* lls = (const float*)d_in[2];
  const float* lv  = (const float*)d_in[3];
  float* out = (float*)d_out;

  unsigned short* xs = (unsigned short*)d_ws;                       // 32 MiB
  unsigned short* Wt = xs + (size_t)BATCH * DIN;                    // 24 MiB

  cast_x_kernel<<<BATCH * DIN / 8 / 256, 256, 0, stream>>>(
      (const float4*)x, lls, (ushort8v*)xs);

  transpose_w_kernel<<<dim3(DFEAT / 64, DIN / 32, 3), dim3(256), 0, stream>>>(W, Wt);

  sketch_gemm_kernel<<<(BATCH / 128) * (DFEAT / 128), 512, 0, stream>>>(xs, Wt, lv, out);
}

// Round 3
// 799.439 us; speedup vs baseline: 1.0139x; 1.0139x over previous
//
#include <hip/hip_runtime.h>

// PolynomialSketch: out[b,o] = (1/64)*exp(0.5*lv) * prod_k( sum_i x[b,i]*exp(-lls)*W[k,i,o] )
// B=16384, D_IN=1024, D_FEAT=4096, DEGREE=3

#define BATCH 16384
#define DIN   1024
#define DFEAT 4096

typedef short short8 __attribute__((ext_vector_type(8)));
typedef float f32x4  __attribute__((ext_vector_type(4)));
typedef unsigned short ushort8v __attribute__((ext_vector_type(8)));

__device__ __forceinline__ unsigned short f2bf(float f) {
  unsigned int u = __float_as_uint(f);
  u += 0x7FFFu + ((u >> 16) & 1u);   // round-to-nearest-even
  return (unsigned short)(u >> 16);
}

// ---- prelude 1: xs_bf16[b,i] = bf16(x[b,i] * exp(-log_ls)) ----
__global__ void cast_x_kernel(const float4* __restrict__ x,
                              const float* __restrict__ log_ls,
                              ushort8v* __restrict__ xs) {
  float inv = expf(-log_ls[0]);
  int i = blockIdx.x * 256 + threadIdx.x;
  float4 v0 = x[i * 2];
  float4 v1 = x[i * 2 + 1];
  ushort8v o;
  o[0] = f2bf(v0.x * inv); o[1] = f2bf(v0.y * inv);
  o[2] = f2bf(v0.z * inv); o[3] = f2bf(v0.w * inv);
  o[4] = f2bf(v1.x * inv); o[5] = f2bf(v1.y * inv);
  o[6] = f2bf(v1.z * inv); o[7] = f2bf(v1.w * inv);
  xs[i] = o;
}

// ---- prelude 2: Wt[d, o, i] = bf16(W[d, i, o]) ----
__global__ void transpose_w_kernel(const float* __restrict__ W,
                                   unsigned short* __restrict__ Wt) {
  __shared__ float tile[32][65];
  int d  = blockIdx.z;
  int i0 = blockIdx.y * 32;   // d_in
  int o0 = blockIdx.x * 64;   // d_feat
  int tid = threadIdx.x;      // 0..255
  const float* src = W + (size_t)d * DIN * DFEAT + (size_t)i0 * DFEAT + o0;
  #pragma unroll
  for (int j = 0; j < 2; ++j) {
    int idx = j * 256 + tid;       // 0..511
    int r = idx >> 4;              // i row 0..31
    int c = (idx & 15) * 4;        // o col
    float4 v = *(const float4*)(src + (size_t)r * DFEAT + c);
    tile[r][c + 0] = v.x; tile[r][c + 1] = v.y;
    tile[r][c + 2] = v.z; tile[r][c + 3] = v.w;
  }
  __syncthreads();
  unsigned short* dst = Wt + (size_t)d * DFEAT * DIN + (size_t)o0 * DIN + i0;
  #pragma unroll
  for (int j = 0; j < 2; ++j) {
    int idx = j * 256 + tid;
    int r = idx >> 3;              // o row 0..63
    int c = (idx & 7) * 4;         // i col
    ushort4 u;
    u.x = f2bf(tile[c + 0][r]);
    u.y = f2bf(tile[c + 1][r]);
    u.z = f2bf(tile[c + 2][r]);
    u.w = f2bf(tile[c + 3][r]);
    *(ushort4*)(dst + (size_t)r * DIN + c) = u;
  }
}

// ---- main fused kernel ----
// BM=128, BN=64, BK=64. 256 threads = 4 waves in 2x2; wave tile 64x32 per degree.
// Double-buffered LDS = 80 KiB -> EXACTLY 2 blocks/CU (160 KiB pool). Round-2
// counters showed the 128 KiB / 1-block/CU variant convoys at every phase
// barrier (MfmaUtil 32%); two independent blocks per CU de-phase and overlap
// (m114 mechanism) on top of the counted-vmcnt pipeline.
// 3 phases per K-tile (one per degree matrix), counted vmcnt (never 0 in the
// main loop), setprio around MFMA clusters.
// Per-wave stage issue per tile: A[4], B0[2], B1[2], B2[2] = 10 in flight.
//   P0 entry: outstanding=10, need A+B0 (6 oldest) -> vmcnt(4)
//   P1 entry: outstanding=10, need B1  (2 oldest)  -> vmcnt(8)
//   P2 entry: outstanding=10, need B2  (2 oldest)  -> vmcnt(8)
// Phase entry is STRICT: waitcnt (own loads) -> s_barrier (all waves) ->
// sched_barrier(0) (compiler fence; rule #18 class hazard).
// LDS tiles: rows of 8 16B-chunks, chunk-XOR-swizzled: phys p = c ^ (row&7),
// applied on the GLOBAL source address (global_load_lds dest must be linear).
__global__ __launch_bounds__(256, 2) void sketch_gemm_kernel(
    const unsigned short* __restrict__ xs,   // [16384][1024] bf16 bits
    const unsigned short* __restrict__ Wt,   // [3][4096][1024] bf16 bits
    const float* __restrict__ log_var,
    float* __restrict__ out) {               // [16384][4096] fp32
  __shared__ unsigned short As[2][128 * 64];       // 32 KB
  __shared__ unsigned short Bs[2][3][64 * 64];     // 48 KB

  const int tid  = threadIdx.x;
  const int lane = tid & 63;
  const int w    = tid >> 6;      // 0..3
  const int wm   = w >> 1;        // wave row (0..1)
  const int wn   = w & 1;         // wave col (0..1)
  const int row  = lane & 15;
  const int quad = lane >> 4;

  // XCD-aware mapping: bid % 8 -> XCD. Each XCD owns 8 bn blocks
  // (B slice = 8*64*1024*2B*3 = 3 MB, fits 4 MB per-XCD L2). Within an
  // XCD, 8 consecutive blocks share one bm (A tile reused from L2).
  // grid = 8192, 8192 % 8 == 0 -> mapping is bijective.
  int bid = blockIdx.x;
  int xcd = bid & 7;
  int t0  = bid >> 3;                // 0..1023 per XCD
  int bn  = (xcd << 3) + (t0 & 7);   // 0..63
  int bm  = t0 >> 3;                 // 0..127

  f32x4 acc[3][4][2];
  #pragma unroll
  for (int d = 0; d < 3; ++d)
    #pragma unroll
    for (int mi = 0; mi < 4; ++mi)
      #pragma unroll
      for (int ni = 0; ni < 2; ++ni)
        acc[d][mi][ni] = (f32x4){0.f, 0.f, 0.f, 0.f};

  const unsigned short* xsrc = xs + (size_t)(bm * 128) * DIN;
  const unsigned short* wsrc = Wt + (size_t)(bn * 64) * DIN;

#define STAGE_A(DSTBUF, K0)                                                    \
  {                                                                            \
    _Pragma("unroll")                                                          \
    for (int j = 0; j < 4; ++j) {                                              \
      int gi = (w << 2) + j;                                                   \
      int gc = (gi << 6) + lane;          /* chunk id 0..1023 */               \
      int mm = gc >> 3;                                                        \
      int cc = (gc & 7) ^ (mm & 7);                                            \
      __builtin_amdgcn_global_load_lds(                                        \
          (const __attribute__((address_space(1))) void*)(                     \
              xsrc + (size_t)mm * DIN + (K0) + cc * 8),                        \
          (__attribute__((address_space(3))) void*)(&As[DSTBUF][gi << 9]),     \
          16, 0, 0);                                                           \
    }                                                                          \
  }

#define STAGE_B(DSTBUF, MAT, K0)                                               \
  {                                                                            \
    _Pragma("unroll")                                                          \
    for (int j = 0; j < 2; ++j) {                                              \
      int gi = (w << 1) + j;                                                   \
      int gc = (gi << 6) + lane;          /* chunk id 0..511 */                \
      int nn = gc >> 3;                                                        \
      int cc = (gc & 7) ^ (nn & 7);                                            \
      __builtin_amdgcn_global_load_lds(                                        \
          (const __attribute__((address_space(1))) void*)(                     \
              wsrc + (size_t)(MAT) * (DFEAT * DIN) + (size_t)nn * DIN + (K0) + cc * 8), \
          (__attribute__((address_space(3))) void*)(&Bs[DSTBUF][MAT][gi << 9]),\
          16, 0, 0);                                                           \
    }                                                                          \
  }

#define READ_A(SRCBUF)                                                         \
  _Pragma("unroll")                                                            \
  for (int mi = 0; mi < 4; ++mi) {                                             \
    _Pragma("unroll")                                                          \
    for (int kh = 0; kh < 2; ++kh) {                                           \
      int mm = wm * 64 + mi * 16 + row;                                        \
      int pp = ((kh << 2) + quad) ^ (mm & 7);                                  \
      a[mi][kh] = *(const short8*)(&As[SRCBUF][mm * 64 + pp * 8]);             \
    }                                                                          \
  }

#define READ_B(SRCBUF, MAT)                                                    \
  _Pragma("unroll")                                                            \
  for (int ni = 0; ni < 2; ++ni) {                                             \
    _Pragma("unroll")                                                          \
    for (int kh = 0; kh < 2; ++kh) {                                           \
      int nn = wn * 32 + ni * 16 + row;                                        \
      int pp = ((kh << 2) + quad) ^ (nn & 7);                                  \
      b[ni][kh] = *(const short8*)(&Bs[SRCBUF][MAT][nn * 64 + pp * 8]);        \
    }                                                                          \
  }

#define MFMA_PHASE(MAT)                                                        \
  __builtin_amdgcn_s_setprio(1);                                               \
  _Pragma("unroll")                                                            \
  for (int mi = 0; mi < 4; ++mi)                                               \
    _Pragma("unroll")                                                          \
    for (int ni = 0; ni < 2; ++ni)                                             \
      _Pragma("unroll")                                                        \
      for (int kh = 0; kh < 2; ++kh)                                           \
        acc[MAT][mi][ni] = __builtin_amdgcn_mfma_f32_16x16x32_bf16(            \
            a[mi][kh], b[ni][kh], acc[MAT][mi][ni], 0, 0, 0);                  \
  __builtin_amdgcn_s_setprio(0);

#define PHASE_ENTRY(N)                                                         \
  asm volatile("s_waitcnt vmcnt(" #N ")" ::: "memory");                        \
  __builtin_amdgcn_s_barrier();                                                \
  __builtin_amdgcn_sched_barrier(0);

  short8 a[4][2];
  short8 b[2][2];

  // prologue: stage tile 0 into buf 0 (issue order A, B0, B1, B2 = 10/wave)
  STAGE_A(0, 0);
  STAGE_B(0, 0, 0);
  STAGE_B(0, 1, 0);
  STAGE_B(0, 2, 0);

  for (int t = 0; t < 15; ++t) {
    const int cur = t & 1;
    const int nxt = cur ^ 1;
    const int kn  = (t + 1) << 6;

    // ---- P0: mat0; prefetch A(t+1), B0(t+1) ----
    PHASE_ENTRY(4);                     // A(t)+B0(t) landed (own), barrier = all
    STAGE_A(nxt, kn);
    STAGE_B(nxt, 0, kn);
    READ_A(cur);
    READ_B(cur, 0);
    MFMA_PHASE(0);

    // ---- P1: mat1; prefetch B1(t+1) ----
    PHASE_ENTRY(8);                     // B1(t) landed
    STAGE_B(nxt, 1, kn);
    READ_B(cur, 1);
    MFMA_PHASE(1);

    // ---- P2: mat2; prefetch B2(t+1) ----
    PHASE_ENTRY(8);                     // B2(t) landed
    STAGE_B(nxt, 2, kn);
    READ_B(cur, 2);
    MFMA_PHASE(2);
  }

  // ---- peeled last tile (t = 15, buf 1, no prefetch; drain 4/2/0) ----
  PHASE_ENTRY(4);
  READ_A(1);
  READ_B(1, 0);
  MFMA_PHASE(0);

  PHASE_ENTRY(2);
  READ_B(1, 1);
  MFMA_PHASE(1);

  PHASE_ENTRY(0);
  READ_B(1, 2);
  MFMA_PHASE(2);

  // epilogue: out = acc0*acc1*acc2 * (1/64)*exp(0.5*lv)
  float sc = 0.015625f * expf(0.5f * log_var[0]);
  #pragma unroll
  for (int mi = 0; mi < 4; ++mi) {
    #pragma unroll
    for (int ni = 0; ni < 2; ++ni) {
      int colg = bn * 64 + wn * 32 + ni * 16 + row;
      int rowg = bm * 128 + wm * 64 + mi * 16 + quad * 4;
      #pragma unroll
      for (int t2 = 0; t2 < 4; ++t2) {
        float v = acc[0][mi][ni][t2] * acc[1][mi][ni][t2] * acc[2][mi][ni][t2] * sc;
        out[(size_t)(rowg + t2) * DFEAT + colg] = v;
      }
    }
  }
#undef STAGE_A
#undef STAGE_B
#undef READ_A
#undef READ_B
#undef MFMA_PHASE
#undef PHASE_ENTRY
}

extern "C" void kernel_launch(void* const* d_in, const int* in_sizes, int n_in,
                              void* d_out, int out_size, void* d_ws, size_t ws_size,
                              hipStream_t stream) {
  const float* x   = (const float*)d_in[0];
  const float* W   = (const float*)d_in[1];
  const float* lls = (const float*)d_in[2];
  const float* lv  = (const float*)d_in[3];
  float* out = (float*)d_out;

  unsigned short* xs = (unsigned short*)d_ws;                       // 32 MiB
  unsigned short* Wt = xs + (size_t)BATCH * DIN;                    // 24 MiB

  cast_x_kernel<<<BATCH * DIN / 8 / 256, 256, 0, stream>>>(
      (const float4*)x, lls, (ushort8v*)xs);

  transpose_w_kernel<<<dim3(DFEAT / 64, DIN / 32, 3), dim3(256), 0, stream>>>(W, Wt);

  sketch_gemm_kernel<<<(BATCH / 128) * (DFEAT / 64), 256, 0, stream>>>(xs, Wt, lv, out);
}

// Round 4
// 712.187 us; speedup vs baseline: 1.1381x; 1.1225x over previous
//
#include <hip/hip_runtime.h>

// PolynomialSketch: out[b,o] = (1/64)*exp(0.5*lv) * prod_k( sum_i x[b,i]*exp(-lls)*W[k,i,o] )
// B=16384, D_IN=1024, D_FEAT=4096, DEGREE=3

#define BATCH 16384
#define DIN   1024
#define DFEAT 4096

typedef short short8 __attribute__((ext_vector_type(8)));
typedef float f32x4  __attribute__((ext_vector_type(4)));
typedef unsigned short ushort8v __attribute__((ext_vector_type(8)));

__device__ __forceinline__ unsigned short f2bf(float f) {
  unsigned int u = __float_as_uint(f);
  u += 0x7FFFu + ((u >> 16) & 1u);   // round-to-nearest-even
  return (unsigned short)(u >> 16);
}

// ---- prelude 1: xs_bf16[b,i] = bf16(x[b,i] * exp(-log_ls)) ----
__global__ void cast_x_kernel(const float4* __restrict__ x,
                              const float* __restrict__ log_ls,
                              ushort8v* __restrict__ xs) {
  float inv = expf(-log_ls[0]);
  int i = blockIdx.x * 256 + threadIdx.x;
  float4 v0 = x[i * 2];
  float4 v1 = x[i * 2 + 1];
  ushort8v o;
  o[0] = f2bf(v0.x * inv); o[1] = f2bf(v0.y * inv);
  o[2] = f2bf(v0.z * inv); o[3] = f2bf(v0.w * inv);
  o[4] = f2bf(v1.x * inv); o[5] = f2bf(v1.y * inv);
  o[6] = f2bf(v1.z * inv); o[7] = f2bf(v1.w * inv);
  xs[i] = o;
}

// ---- prelude 2: Wt[d, o, i] = bf16(W[d, i, o]) ----
__global__ void transpose_w_kernel(const float* __restrict__ W,
                                   unsigned short* __restrict__ Wt) {
  __shared__ float tile[32][65];
  int d  = blockIdx.z;
  int i0 = blockIdx.y * 32;   // d_in
  int o0 = blockIdx.x * 64;   // d_feat
  int tid = threadIdx.x;      // 0..255
  const float* src = W + (size_t)d * DIN * DFEAT + (size_t)i0 * DFEAT + o0;
  #pragma unroll
  for (int j = 0; j < 2; ++j) {
    int idx = j * 256 + tid;       // 0..511
    int r = idx >> 4;              // i row 0..31
    int c = (idx & 15) * 4;        // o col
    float4 v = *(const float4*)(src + (size_t)r * DFEAT + c);
    tile[r][c + 0] = v.x; tile[r][c + 1] = v.y;
    tile[r][c + 2] = v.z; tile[r][c + 3] = v.w;
  }
  __syncthreads();
  unsigned short* dst = Wt + (size_t)d * DFEAT * DIN + (size_t)o0 * DIN + i0;
  #pragma unroll
  for (int j = 0; j < 2; ++j) {
    int idx = j * 256 + tid;
    int r = idx >> 3;              // o row 0..63
    int c = (idx & 7) * 4;         // i col
    ushort4 u;
    u.x = f2bf(tile[c + 0][r]);
    u.y = f2bf(tile[c + 1][r]);
    u.z = f2bf(tile[c + 2][r]);
    u.w = f2bf(tile[c + 3][r]);
    *(ushort4*)(dst + (size_t)r * DIN + c) = u;
  }
}

// ---- main fused kernel ----
// BM=128, BN=64, BK=64. 256 threads = 4 waves in 2x2; wave tile 64x32 per degree.
// Double-buffered LDS = 80 KiB -> 2 blocks/CU.
//
// ROUND-4 STRUCTURE: m201-style REGISTER READ-AHEAD. Each phase ds_reads the
// fragments for the NEXT phase's MFMA and runs MFMA on fragments read LAST
// phase — the post-barrier critical path is lgkm(near-done) -> MFMA, not
// barrier -> ds_read latency -> MFMA (rounds 2-3 flaw, MfmaUtil stuck at 33%).
// Rotation per tile t (cur buf CB=t&1, next NB):
//   P0: MFMA mat0 (a(t), b0(t));  reads b1(t)  from CB;  stages A,B0(t+1)->NB
//   P1: MFMA mat1 (a(t), b1(t));  reads b2(t)  from CB;  stages B1(t+1)->NB
//   P2: MFMA mat2 (a(t), b2(t));  reads a(t+1),b0(t+1) from NB (confirmed by
//       this phase's vmcnt);       stages B2(t+1)->NB
// Register ping-pong: a0/a1 per tile parity; bx/by swap roles per tile.
// vmcnt ledger (per-wave issue: P0: A4+B0 2, P1: B1 2, P2: B2 2 = 10/tile):
//   P0 entry: outstanding {B1(t)2, B2(t)2}=4,          drain B1(t)   -> vmcnt(2)
//   P1 entry: outstanding {B2(t)2, A+B0(t+1)6}=8,      drain B2(t)   -> vmcnt(6)
//   P2 entry: outstanding {A+B0(t+1)6, B1(t+1)2}=8,    drain A+B0    -> vmcnt(2)
//   prologue: 10 issued, drain A+B0 -> vmcnt(4); tail: 2 / 0.
// Phase entry is STRICT: waitcnt (own loads) -> s_barrier (all waves) ->
// sched_barrier(0) (ds_reads must not hoist above the barrier — rule #18).
// LDS tiles: rows of 8 16B-chunks, chunk-XOR-swizzled: phys p = c ^ (row&7),
// applied on the GLOBAL source address (global_load_lds dest must be linear).
__global__ __launch_bounds__(256, 2) void sketch_gemm_kernel(
    const unsigned short* __restrict__ xs,   // [16384][1024] bf16 bits
    const unsigned short* __restrict__ Wt,   // [3][4096][1024] bf16 bits
    const float* __restrict__ log_var,
    float* __restrict__ out) {               // [16384][4096] fp32
  __shared__ unsigned short As[2][128 * 64];       // 32 KB
  __shared__ unsigned short Bs[2][3][64 * 64];     // 48 KB

  const int tid  = threadIdx.x;
  const int lane = tid & 63;
  const int w    = tid >> 6;      // 0..3
  const int wm   = w >> 1;        // wave row (0..1)
  const int wn   = w & 1;         // wave col (0..1)
  const int row  = lane & 15;
  const int quad = lane >> 4;

  // XCD-aware mapping: bid % 8 -> XCD; 8 bn blocks per XCD slice (3 MB of B
  // fits 4 MB per-XCD L2); 8 consecutive blocks share one bm. 8192 % 8 == 0.
  int bid = blockIdx.x;
  int xcd = bid & 7;
  int t0  = bid >> 3;                // 0..1023 per XCD
  int bn  = (xcd << 3) + (t0 & 7);   // 0..63
  int bm  = t0 >> 3;                 // 0..127

  f32x4 acc[3][4][2];
  #pragma unroll
  for (int d = 0; d < 3; ++d)
    #pragma unroll
    for (int mi = 0; mi < 4; ++mi)
      #pragma unroll
      for (int ni = 0; ni < 2; ++ni)
        acc[d][mi][ni] = (f32x4){0.f, 0.f, 0.f, 0.f};

  const unsigned short* xsrc = xs + (size_t)(bm * 128) * DIN;
  const unsigned short* wsrc = Wt + (size_t)(bn * 64) * DIN;

#define STAGE_A(DSTBUF, K0)                                                    \
  {                                                                            \
    _Pragma("unroll")                                                          \
    for (int j = 0; j < 4; ++j) {                                              \
      int gi = (w << 2) + j;                                                   \
      int gc = (gi << 6) + lane;          /* chunk id 0..1023 */               \
      int mm = gc >> 3;                                                        \
      int cc = (gc & 7) ^ (mm & 7);                                            \
      __builtin_amdgcn_global_load_lds(                                        \
          (const __attribute__((address_space(1))) void*)(                     \
              xsrc + (size_t)mm * DIN + (K0) + cc * 8),                        \
          (__attribute__((address_space(3))) void*)(&As[DSTBUF][gi << 9]),     \
          16, 0, 0);                                                           \
    }                                                                          \
  }

#define STAGE_B(DSTBUF, MAT, K0)                                               \
  {                                                                            \
    _Pragma("unroll")                                                          \
    for (int j = 0; j < 2; ++j) {                                              \
      int gi = (w << 1) + j;                                                   \
      int gc = (gi << 6) + lane;          /* chunk id 0..511 */                \
      int nn = gc >> 3;                                                        \
      int cc = (gc & 7) ^ (nn & 7);                                            \
      __builtin_amdgcn_global_load_lds(                                        \
          (const __attribute__((address_space(1))) void*)(                     \
              wsrc + (size_t)(MAT) * (DFEAT * DIN) + (size_t)nn * DIN + (K0) + cc * 8), \
          (__attribute__((address_space(3))) void*)(&Bs[DSTBUF][MAT][gi << 9]),\
          16, 0, 0);                                                           \
    }                                                                          \
  }

#define READ_A(SRCBUF, DST)                                                    \
  _Pragma("unroll")                                                            \
  for (int mi = 0; mi < 4; ++mi) {                                             \
    _Pragma("unroll")                                                          \
    for (int kh = 0; kh < 2; ++kh) {                                           \
      int mm = wm * 64 + mi * 16 + row;                                        \
      int pp = ((kh << 2) + quad) ^ (mm & 7);                                  \
      DST[mi][kh] = *(const short8*)(&As[SRCBUF][mm * 64 + pp * 8]);           \
    }                                                                          \
  }

#define READ_B(SRCBUF, MAT, DST)                                               \
  _Pragma("unroll")                                                            \
  for (int ni = 0; ni < 2; ++ni) {                                             \
    _Pragma("unroll")                                                          \
    for (int kh = 0; kh < 2; ++kh) {                                           \
      int nn = wn * 32 + ni * 16 + row;                                        \
      int pp = ((kh << 2) + quad) ^ (nn & 7);                                  \
      DST[ni][kh] = *(const short8*)(&Bs[SRCBUF][MAT][nn * 64 + pp * 8]);      \
    }                                                                          \
  }

// MFMA on fragments read in the PREVIOUS phase (compiler data-deps handle
// lgkm waits; fragments are a full phase old so waits are ~free).
#define MFMA_P(MAT, AARR, BARR)                                                \
  __builtin_amdgcn_s_setprio(1);                                               \
  _Pragma("unroll")                                                            \
  for (int mi = 0; mi < 4; ++mi)                                               \
    _Pragma("unroll")                                                          \
    for (int ni = 0; ni < 2; ++ni)                                             \
      _Pragma("unroll")                                                        \
      for (int kh = 0; kh < 2; ++kh)                                           \
        acc[MAT][mi][ni] = __builtin_amdgcn_mfma_f32_16x16x32_bf16(            \
            AARR[mi][kh], BARR[ni][kh], acc[MAT][mi][ni], 0, 0, 0);            \
  __builtin_amdgcn_s_setprio(0);                                               \
  __builtin_amdgcn_sched_barrier(0);

#define ENTRY(N)                                                               \
  asm volatile("s_waitcnt vmcnt(" #N ")" ::: "memory");                        \
  __builtin_amdgcn_s_barrier();                                                \
  __builtin_amdgcn_sched_barrier(0);

// One K-tile, 3 phases. T runtime; AC/AA = a-frag cur/next; BX/BY = b-frag
// ping-pong; CB/NB = LDS buffer indices (compile-time 0/1).
#define TILE_BODY(T, AC, AA, BX, BY, CB, NB)                                   \
  {                                                                            \
    const int kn_ = ((T) + 1) << 6;                                            \
    /* P0: mat0; read b1(t); stage A,B0(t+1) */                                \
    ENTRY(2);                                                                  \
    READ_B(CB, 1, BY);                                                         \
    STAGE_A(NB, kn_);                                                          \
    STAGE_B(NB, 0, kn_);                                                       \
    __builtin_amdgcn_sched_barrier(0);                                         \
    MFMA_P(0, AC, BX);                                                         \
    /* P1: mat1; read b2(t); stage B1(t+1) */                                  \
    ENTRY(6);                                                                  \
    READ_B(CB, 2, BX);                                                         \
    STAGE_B(NB, 1, kn_);                                                       \
    __builtin_amdgcn_sched_barrier(0);                                         \
    MFMA_P(1, AC, BY);                                                         \
    /* P2: mat2; read a(t+1), b0(t+1) from NB; stage B2(t+1) */                \
    ENTRY(2);                                                                  \
    READ_A(NB, AA);                                                            \
    READ_B(NB, 0, BY);                                                         \
    STAGE_B(NB, 2, kn_);                                                       \
    __builtin_amdgcn_sched_barrier(0);                                         \
    MFMA_P(2, AC, BX);                                                         \
  }

  short8 a0[4][2], a1[4][2];   // A fragments, tile-parity ping-pong
  short8 bx[2][2], by[2][2];   // B fragments, role-swap per tile

  // prologue: stage tile 0 into buf 0 (A, B0, B1, B2 = 10 loads/wave),
  // then preload a(0), b0(0) into registers.
  STAGE_A(0, 0);
  STAGE_B(0, 0, 0);
  STAGE_B(0, 1, 0);
  STAGE_B(0, 2, 0);
  asm volatile("s_waitcnt vmcnt(4)" ::: "memory");   // A(0)+B0(0) landed
  __builtin_amdgcn_s_barrier();
  __builtin_amdgcn_sched_barrier(0);
  READ_A(0, a0);
  READ_B(0, 0, bx);

  #pragma unroll 1
  for (int i = 0; i < 7; ++i) {
    const int t = i * 2;
    TILE_BODY(t,     a0, a1, bx, by, 0, 1);
    TILE_BODY(t + 1, a1, a0, by, bx, 1, 0);
  }
  TILE_BODY(14, a0, a1, bx, by, 0, 1);

  // ---- tail: tile 15 (buf 1; AC=a1, b0(15) in by; no prefetch) ----
  ENTRY(2);                       // drain B1(15)
  READ_B(1, 1, bx);
  __builtin_amdgcn_sched_barrier(0);
  MFMA_P(0, a1, by);

  ENTRY(0);                       // drain B2(15)
  READ_B(1, 2, by);
  __builtin_amdgcn_sched_barrier(0);
  MFMA_P(1, a1, bx);

  MFMA_P(2, a1, by);

  // epilogue: out = acc0*acc1*acc2 * (1/64)*exp(0.5*lv)
  float sc = 0.015625f * expf(0.5f * log_var[0]);
  #pragma unroll
  for (int mi = 0; mi < 4; ++mi) {
    #pragma unroll
    for (int ni = 0; ni < 2; ++ni) {
      int colg = bn * 64 + wn * 32 + ni * 16 + row;
      int rowg = bm * 128 + wm * 64 + mi * 16 + quad * 4;
      #pragma unroll
      for (int t2 = 0; t2 < 4; ++t2) {
        float v = acc[0][mi][ni][t2] * acc[1][mi][ni][t2] * acc[2][mi][ni][t2] * sc;
        out[(size_t)(rowg + t2) * DFEAT + colg] = v;
      }
    }
  }
#undef STAGE_A
#undef STAGE_B
#undef READ_A
#undef READ_B
#undef MFMA_P
#undef ENTRY
#undef TILE_BODY
}

extern "C" void kernel_launch(void* const* d_in, const int* in_sizes, int n_in,
                              void* d_out, int out_size, void* d_ws, size_t ws_size,
                              hipStream_t stream) {
  const float* x   = (const float*)d_in[0];
  const float* W   = (const float*)d_in[1];
  const float* lls = (const float*)d_in[2];
  const float* lv  = (const float*)d_in[3];
  float* out = (float*)d_out;

  unsigned short* xs = (unsigned short*)d_ws;                       // 32 MiB
  unsigned short* Wt = xs + (size_t)BATCH * DIN;                    // 24 MiB

  cast_x_kernel<<<BATCH * DIN / 8 / 256, 256, 0, stream>>>(
      (const float4*)x, lls, (ushort8v*)xs);

  transpose_w_kernel<<<dim3(DFEAT / 64, DIN / 32, 3), dim3(256), 0, stream>>>(W, Wt);

  sketch_gemm_kernel<<<(BATCH / 128) * (DFEAT / 64), 256, 0, stream>>>(xs, Wt, lv, out);
}